// Round 8
// baseline (212.601 us; speedup 1.0000x reference)
//
#include <hip/hip_runtime.h>
#include <hip/hip_bf16.h>
#include <cstddef>

#define DMODEL 1024
#define DI     2048
#define DS     16
#define LSEQ   2048
#define BATCH  2
#define NC     128           // number of scan chunks
#define TCH    (LSEQ / NC)   // 16 steps per chunk

typedef __attribute__((ext_vector_type(8))) short short8;
typedef __attribute__((ext_vector_type(4))) float f32x4;
typedef __attribute__((ext_vector_type(2))) float f32x2;
typedef __attribute__((ext_vector_type(8))) unsigned short us8;

__device__ __forceinline__ unsigned short f2bf(float f) {
    unsigned int u = __float_as_uint(f);
    unsigned int r = (u + 0x7fff + ((u >> 16) & 1)) >> 16;   // RNE
    return (unsigned short)r;
}
__device__ __forceinline__ float bf2f(unsigned short b) {
    return __uint_as_float(((unsigned int)b) << 16);
}

__device__ __forceinline__ float fexp2(float x) {
#if __has_builtin(__builtin_amdgcn_exp2f)
    return __builtin_amdgcn_exp2f(x);
#else
    return exp2f(x);
#endif
}
__device__ __forceinline__ float flog2(float x) {
#if __has_builtin(__builtin_amdgcn_logf)
    return __builtin_amdgcn_logf(x);
#else
    return log2f(x);
#endif
}

#define LOG2E 1.4426950408889634f
#define RLOG2E 0.6931471805599453f

__device__ __forceinline__ float softplus_f(float v) {
    return (v > 20.f) ? v : flog2(1.f + fexp2(v * LOG2E)) * RLOG2E;
}

__device__ __forceinline__ void gload_lds16(const void* g, void* l) {
    __builtin_amdgcn_global_load_lds(
        (const __attribute__((address_space(1))) unsigned int*)g,
        (__attribute__((address_space(3))) unsigned int*)l, 16, 0, 0);
}

// ---------------------------------------------------------------------------
// f32 -> bf16 convert
// ---------------------------------------------------------------------------
__global__ void cvt_bf16(const float* __restrict__ in, unsigned short* __restrict__ out, int n8) {
    int i = blockIdx.x * 256 + threadIdx.x;
    if (i >= n8) return;
    const float4* p = reinterpret_cast<const float4*>(in) + i * 2;
    float4 v0 = p[0], v1 = p[1];
    us8 o;
    o[0] = f2bf(v0.x); o[1] = f2bf(v0.y); o[2] = f2bf(v0.z); o[3] = f2bf(v0.w);
    o[4] = f2bf(v1.x); o[5] = f2bf(v1.y); o[6] = f2bf(v1.z); o[7] = f2bf(v1.w);
    *reinterpret_cast<us8*>(out + (size_t)i * 8) = o;
}

// W_x (33x2048 f32) -> bf16 padded to 48 rows
__global__ void prep_wx(const float* __restrict__ wx, unsigned short* __restrict__ out) {
    int i = blockIdx.x * 256 + threadIdx.x;
    if (i >= 48 * 2048 / 8) return;
    size_t o = (size_t)i * 8;
    int row = (int)(o >> 11);
    us8 v;
    if (row < 33) {
        const float4* p = reinterpret_cast<const float4*>(wx + o);
        float4 v0 = p[0], v1 = p[1];
        v[0] = f2bf(v0.x); v[1] = f2bf(v0.y); v[2] = f2bf(v0.z); v[3] = f2bf(v0.w);
        v[4] = f2bf(v1.x); v[5] = f2bf(v1.y); v[6] = f2bf(v1.z); v[7] = f2bf(v1.w);
    } else {
        v = (us8)0;
    }
    *reinterpret_cast<us8*>(out + o) = v;
}

// A table, transposed + log2e-folded
__global__ void prep_A(const float* __restrict__ A_log, float* __restrict__ At2) {
    int i = blockIdx.x * 256 + threadIdx.x;
    if (i >= DS * DI) return;
    int n = i / DI, d = i % DI;
    At2[i] = -__expf(A_log[d * DS + n]) * LOG2E;
}

// ---------------------------------------------------------------------------
// GEMM1, 8-phase schedule (guide §5 template): 256x256 tile, BK=64, 8 waves
// (2Mx4N, wave owns 128x64, acc[8][4]), LDS 2-dbuf A + 2-dbuf B = 128 KiB,
// counted vmcnt(6) once per K-tile, 8-slot XOR swizzle, bf16 out.
// M=N=4096, K=1024 fixed (T1=16 K-tiles).
// Staging ring: t.p0 stages part3 of tile t+1 (other dbuf); t.p1..p3 stage
// parts 0..2 of tile t+2 (same dbuf; region dead after phase q-1's barrier).
// ---------------------------------------------------------------------------
#define T1 16
__global__ __launch_bounds__(512, 1)
void gemm1_8ph(const unsigned short* __restrict__ A, const unsigned short* __restrict__ B,
               unsigned short* __restrict__ C) {
    __shared__ unsigned short ldsA[2][256 * 64];   // 2 x 32 KiB
    __shared__ unsigned short ldsB[2][256 * 64];   // 2 x 32 KiB

    const int tid = threadIdx.x;
    const int wid = tid >> 6, ln = tid & 63;
    const int wm = wid >> 2, wn = wid & 3;         // 2 x 4 waves; wave owns 128x64

    int wg = blockIdx.x;
    wg = (wg & 7) * 32 + (wg >> 3);                // XCD swizzle (256 % 8 == 0)
    const int m0 = (wg >> 4) * 256;
    const int n0 = (wg & 15) * 256;

    // staging coords: 1 load/thread covers a 64-row x 64-k part (8 KiB)
    const int rr = tid >> 3;                       // 0..63
    const int s  = tid & 7;                        // LDS 16B slot within row
    const int sgk = (s ^ (rr & 7)) * 8;            // inverse-swizzled global k-elem

    // frag coords
    const int fr = ln & 15;
    const int fku = (ln >> 4);                     // 0..3 (k-unit within 32-k half)

    f32x4 acc[8][4] = {};

    // stageA part p of tile t into ldsA[buf]: rows {p*32..+31} u {128+p*32..+31}
    #define STAGE_A(buf, t, p)                                                           \
        do {                                                                             \
            int row_ = (p) * 32 + (rr & 31) + (rr >> 5) * 128;                           \
            gload_lds16(A + (size_t)(m0 + row_) * 1024 + (t) * 64 + sgk,                 \
                        &ldsA[buf][row_ * 64 + s * 8]);                                  \
        } while (0)
    // stageB part p of tile t: rows p*64..p*64+63
    #define STAGE_B(buf, t, p)                                                           \
        do {                                                                             \
            int row_ = (p) * 64 + rr;                                                    \
            gload_lds16(B + (size_t)(n0 + row_) * 1024 + (t) * 64 + sgk,                 \
                        &ldsB[buf][row_ * 64 + s * 8]);                                  \
        } while (0)

    // prologue: tile0 full (8 loads), tile1 parts 0..2 (6 loads)
    #pragma unroll
    for (int p = 0; p < 4; ++p) { STAGE_A(0, 0, p); STAGE_B(0, 0, p); }
    #pragma unroll
    for (int p = 0; p < 3; ++p) { STAGE_A(1, 1, p); STAGE_B(1, 1, p); }
    asm volatile("s_waitcnt vmcnt(6)" ::: "memory");   // tile0 landed
    __builtin_amdgcn_s_barrier();
    __builtin_amdgcn_sched_barrier(0);

    #pragma unroll 2
    for (int t = 0; t < T1; ++t) {
        const int c = t & 1;
        short8 bfr[4][2];

        #pragma unroll
        for (int q = 0; q < 4; ++q) {
            // ---- ds_read this phase's fragments (latency overlaps barrier) ----
            short8 afr[2][2];
            #pragma unroll
            for (int m = 0; m < 2; ++m)
                #pragma unroll
                for (int kk = 0; kk < 2; ++kk) {
                    int row = wm * 128 + q * 32 + m * 16 + fr;
                    int slot = (kk * 4 + fku) ^ (row & 7);
                    afr[m][kk] = *reinterpret_cast<const short8*>(&ldsA[c][row * 64 + slot * 8]);
                }
            if (q == 0) {
                #pragma unroll
                for (int n = 0; n < 4; ++n)
                    #pragma unroll
                    for (int kk = 0; kk < 2; ++kk) {
                        int row = wn * 64 + n * 16 + fr;
                        int slot = (kk * 4 + fku) ^ (row & 7);
                        bfr[n][kk] = *reinterpret_cast<const short8*>(&ldsB[c][row * 64 + slot * 8]);
                    }
            }
            // ---- stage 2 half-tile loads (ring: p0 -> t+1 part3; p1..p3 -> t+2 parts q-1)
            if (q == 0) {
                if (t + 1 < T1) { STAGE_A(c ^ 1, t + 1, 3); STAGE_B(c ^ 1, t + 1, 3); }
            } else {
                if (t + 2 < T1) { STAGE_A(c, t + 2, q - 1); STAGE_B(c, t + 2, q - 1); }
            }

            __builtin_amdgcn_s_barrier();
            asm volatile("s_waitcnt lgkmcnt(0)" ::: "memory");
            __builtin_amdgcn_sched_barrier(0);

            __builtin_amdgcn_s_setprio(1);
            #pragma unroll
            for (int m = 0; m < 2; ++m)
                #pragma unroll
                for (int n = 0; n < 4; ++n) {
                    acc[q * 2 + m][n] = __builtin_amdgcn_mfma_f32_16x16x32_bf16(
                        afr[m][0], bfr[n][0], acc[q * 2 + m][n], 0, 0, 0);
                    acc[q * 2 + m][n] = __builtin_amdgcn_mfma_f32_16x16x32_bf16(
                        afr[m][1], bfr[n][1], acc[q * 2 + m][n], 0, 0, 0);
                }
            __builtin_amdgcn_s_setprio(0);
            __builtin_amdgcn_sched_barrier(0);

            if (q == 3) {   // once per K-tile, counted (0 only in the tail)
                if (t < T1 - 2) asm volatile("s_waitcnt vmcnt(6)" ::: "memory");
                else            asm volatile("s_waitcnt vmcnt(0)" ::: "memory");
            }
            __builtin_amdgcn_s_barrier();
            __builtin_amdgcn_sched_barrier(0);
        }
    }
    #undef STAGE_A
    #undef STAGE_B

    const int cr = (ln >> 4) * 4, cc = ln & 15;
    #pragma unroll
    for (int i = 0; i < 8; ++i) {
        int row = m0 + wm * 128 + (i >> 1) * 32 + (i & 1) * 16 + cr;
        #pragma unroll
        for (int j = 0; j < 4; ++j) {
            int col = n0 + wn * 64 + j * 16 + cc;
            #pragma unroll
            for (int r = 0; r < 4; ++r)
                C[(size_t)(row + r) * 4096 + col] = f2bf(acc[i][j][r]);
        }
    }
}

// ---------------------------------------------------------------------------
// GEMM3: 128x64 tile, 4 waves (2x2), BK=32, 4-deep pipeline, counted vmcnt,
// k-unit XOR swizzle, f32 out.  M=4096, N=1024, K=2048 fixed; grid 512.
// ---------------------------------------------------------------------------
#define NT3 64
__global__ __launch_bounds__(256, 2)
void gemm3_pipe(const unsigned short* __restrict__ A, int lda,
                const unsigned short* __restrict__ B,
                float* __restrict__ C) {
    __shared__ unsigned short As[4][128 * 32];   // 32 KiB
    __shared__ unsigned short Bs[4][64 * 32];    // 16 KiB

    const int tid = threadIdx.x;
    const int wid = tid >> 6, ln = tid & 63;
    const int wm = wid >> 1, wn = wid & 1;       // wave owns 64x32

    int wg = blockIdx.x;
    wg = (wg & 7) * 64 + (wg >> 3);              // XCD swizzle (512 % 8 == 0)
    const int m0 = (wg >> 4) * 128;
    const int n0 = (wg & 15) * 64;

    const int srow = tid >> 2;                   // 0..63
    const int sun  = tid & 3;
    const int ksrc = ((sun ^ ((srow >> 1) & 3)) * 8);

    const int fr = ln & 15;
    const int fku = (ln >> 4);

    f32x4 acc[4][2] = {};

    #define STAGE3(kt)                                                                     \
        do {                                                                               \
            const int bq_ = (kt) & 3;                                                      \
            gload_lds16(A + (size_t)(m0 + srow) * lda + (kt) * 32 + ksrc,                  \
                        &As[bq_][srow * 32 + sun * 8]);                                    \
            gload_lds16(A + (size_t)(m0 + 64 + srow) * lda + (kt) * 32 + ksrc,             \
                        &As[bq_][(64 + srow) * 32 + sun * 8]);                             \
            gload_lds16(B + (size_t)(n0 + srow) * 2048 + (kt) * 32 + ksrc,                 \
                        &Bs[bq_][srow * 32 + sun * 8]);                                    \
        } while (0)

    STAGE3(0); STAGE3(1); STAGE3(2);
    asm volatile("s_waitcnt vmcnt(6)" ::: "memory");   // K-tile 0 landed
    __builtin_amdgcn_s_barrier();
    __builtin_amdgcn_sched_barrier(0);

    for (int kt = 0; kt < NT3; ++kt) {
        const int bq = kt & 3;
        if (kt + 3 < NT3) STAGE3(kt + 3);

        short8 af[4], bfr[2];
        #pragma unroll
        for (int i = 0; i < 4; ++i) {
            int r = wm * 64 + i * 16 + fr;
            int u = fku ^ ((r >> 1) & 3);
            af[i] = *reinterpret_cast<const short8*>(&As[bq][r * 32 + u * 8]);
        }
        #pragma unroll
        for (int j = 0; j < 2; ++j) {
            int r = wn * 32 + j * 16 + fr;
            int u = fku ^ ((r >> 1) & 3);
            bfr[j] = *reinterpret_cast<const short8*>(&Bs[bq][r * 32 + u * 8]);
        }
        __builtin_amdgcn_sched_barrier(0);
        __builtin_amdgcn_s_setprio(1);
        #pragma unroll
        for (int i = 0; i < 4; ++i)
            #pragma unroll
            for (int j = 0; j < 2; ++j)
                acc[i][j] = __builtin_amdgcn_mfma_f32_16x16x32_bf16(af[i], bfr[j], acc[i][j], 0, 0, 0);
        __builtin_amdgcn_s_setprio(0);
        __builtin_amdgcn_sched_barrier(0);

        if (kt < NT3 - 3)       asm volatile("s_waitcnt vmcnt(6)" ::: "memory");
        else if (kt == NT3 - 3) asm volatile("s_waitcnt vmcnt(3)" ::: "memory");
        else if (kt == NT3 - 2) asm volatile("s_waitcnt vmcnt(0)" ::: "memory");
        __builtin_amdgcn_s_barrier();
        __builtin_amdgcn_sched_barrier(0);
    }
    #undef STAGE3

    const int cr = (ln >> 4) * 4, cc = ln & 15;
    #pragma unroll
    for (int i = 0; i < 4; ++i) {
        int row = m0 + wm * 64 + i * 16 + cr;
        #pragma unroll
        for (int j = 0; j < 2; ++j) {
            int col = n0 + wn * 32 + j * 16 + cc;
            #pragma unroll
            for (int r = 0; r < 4; ++r)
                C[(size_t)(row + r) * 1024 + col] = acc[i][j][r];
        }
    }
}

// ---------------------------------------------------------------------------
// depthwise causal conv (width 4) + bias + SiLU; bf16 in (XZb), bf16 out
// ---------------------------------------------------------------------------
__global__ void conv_silu(const unsigned short* __restrict__ xzb, const float* __restrict__ cw,
                          const float* __restrict__ cb, unsigned short* __restrict__ xactb) {
    int i = blockIdx.x * 256 + threadIdx.x;        // over B*L*DI/8
    if (i >= BATCH * LSEQ * DI / 8) return;
    int d0 = (i % (DI / 8)) * 8;
    int l  = (i / (DI / 8)) % LSEQ;
    int b  = i / ((DI / 8) * LSEQ);

    float4 w[8];
    #pragma unroll
    for (int j = 0; j < 8; ++j)
        w[j] = *reinterpret_cast<const float4*>(cw + (d0 + j) * 4);

    float acc[8];
    #pragma unroll
    for (int j = 0; j < 8; ++j) acc[j] = cb[d0 + j];

    #pragma unroll
    for (int t = 0; t < 4; ++t) {
        int ls = l - 3 + t;
        if (ls >= 0) {
            us8 v = *reinterpret_cast<const us8*>(xzb + (size_t)(b * LSEQ + ls) * 4096 + d0);
            #pragma unroll
            for (int j = 0; j < 8; ++j) {
                float wt = (t == 0) ? w[j].x : (t == 1) ? w[j].y : (t == 2) ? w[j].z : w[j].w;
                acc[j] += bf2f(v[j]) * wt;
            }
        }
    }
    us8 o;
    #pragma unroll
    for (int j = 0; j < 8; ++j) {
        float v = acc[j] / (1.f + __expf(-acc[j]));
        o[j] = f2bf(v);
    }
    *reinterpret_cast<us8*>(xactb + (size_t)i * 8) = o;
}

// ---------------------------------------------------------------------------
// skinny MFMA GEMM for proj: partials -> PROJP[row*144 + kz*36 + col]
// ---------------------------------------------------------------------------
__global__ __launch_bounds__(256)
void gemm_proj_mfma(const unsigned short* __restrict__ Xb, const unsigned short* __restrict__ Wxb,
                    float* __restrict__ projp) {
    __shared__ unsigned short As[64 * 32];
    __shared__ unsigned short Bs[48 * 32];

    const int tid = threadIdx.x;
    const int wv = tid >> 6, ln = tid & 63;
    const int m0 = blockIdx.x * 64;
    const int kz = blockIdx.y;
    const int srow = tid >> 2, skoff = (tid & 3) * 8;
    const int fr = ln & 15, fk = (ln >> 4) * 8;

    f32x4 acc[3] = {};

    const int k0base = kz * 512;
    for (int k0 = k0base; k0 < k0base + 512; k0 += 32) {
        gload_lds16(Xb + (size_t)(m0 + srow) * DI + k0 + skoff, &As[wv * 512]);
        if (wv < 3)
            gload_lds16(Wxb + (size_t)srow * DI + k0 + skoff, &Bs[wv * 512]);
        __syncthreads();

        short8 af = *reinterpret_cast<const short8*>(&As[(wv * 16 + fr) * 32 + fk]);
        #pragma unroll
        for (int j = 0; j < 3; ++j) {
            short8 bf_ = *reinterpret_cast<const short8*>(&Bs[(j * 16 + fr) * 32 + fk]);
            acc[j] = __builtin_amdgcn_mfma_f32_16x16x32_bf16(af, bf_, acc[j], 0, 0, 0);
        }
        __syncthreads();
    }

    const int cr = (ln >> 4) * 4, cc = ln & 15;
    #pragma unroll
    for (int j = 0; j < 3; ++j) {
        int col = j * 16 + cc;
        if (col < 33) {
            #pragma unroll
            for (int r = 0; r < 4; ++r) {
                int row = m0 + wv * 16 + cr + r;
                projp[(size_t)row * 144 + kz * 36 + col] = acc[j][r];
            }
        }
    }
}

// combine 4 K-split partials
__global__ void proj_combine(const float* __restrict__ projp, float* __restrict__ proj) {
    int idx = blockIdx.x * 256 + threadIdx.x;
    if (idx >= BATCH * LSEQ * 33) return;
    int row = idx / 33, col = idx % 33;
    float s = 0.f;
    #pragma unroll
    for (int kz = 0; kz < 4; ++kz)
        s += projp[(size_t)row * 144 + kz * 36 + col];
    proj[(size_t)row * 36 + col] = s;
}

// ---------------------------------------------------------------------------
// scan phase 1: local scan (h0=0); y_local (bf16), S prefix (bf16 into XZb
// x-cols), Hend (bf16), dtsum (f32)
// ---------------------------------------------------------------------------
__global__ __launch_bounds__(256)
void scan_phase1(const unsigned short* __restrict__ xactb, const float* __restrict__ proj,
                 const float* __restrict__ At2, const float* __restrict__ W_dt,
                 const float* __restrict__ b_dt, unsigned short* __restrict__ Hend,
                 float* __restrict__ dtsum, unsigned short* __restrict__ yloc,
                 unsigned short* __restrict__ XZb) {
    const int d = blockIdx.x * 256 + threadIdx.x;
    const int c = blockIdx.y;
    const int b = blockIdx.z;

    f32x2 A2[DS / 2], h2[DS / 2];
    #pragma unroll
    for (int p = 0; p < DS / 2; ++p) {
        A2[p] = (f32x2){At2[(2 * p) * DI + d], At2[(2 * p + 1) * DI + d]};
        h2[p] = (f32x2){0.f, 0.f};
    }
    const float wdt = W_dt[d], bdt = b_dt[d];
    float ssum = 0.f;

    const int l0 = c * TCH;
    #pragma unroll 2
    for (int l = l0; l < l0 + TCH; ++l) {
        const size_t row = (size_t)(b * LSEQ + l);
        const float* pr = proj + row * 36;
        float dt = softplus_f(pr[32] * wdt + bdt);
        ssum += dt;
        XZb[row * 4096 + d] = f2bf(ssum);
        float x = bf2f(xactb[row * DI + d]);
        float xdt = x * dt;
        f32x2 xdt2 = (f32x2){xdt, xdt};
        f32x2 y2 = (f32x2){0.f, 0.f};
        #pragma unroll
        for (int p = 0; p < DS / 2; ++p) {
            f32x2 t = A2[p] * dt;
            f32x2 e2 = (f32x2){fexp2(t.x), fexp2(t.y)};
            h2[p] = e2 * h2[p] + xdt2 * (f32x2){pr[2 * p], pr[2 * p + 1]};
            y2 += h2[p] * (f32x2){pr[16 + 2 * p], pr[17 + 2 * p]};
        }
        yloc[row * DI + d] = f2bf(y2.x + y2.y);
    }
    size_t base = ((size_t)(b * NC + c) * DS) * DI + d;
    #pragma unroll
    for (int p = 0; p < DS / 2; ++p) {
        Hend[base + (size_t)(2 * p) * DI]     = f2bf(h2[p].x);
        Hend[base + (size_t)(2 * p + 1) * DI] = f2bf(h2[p].y);
    }
    dtsum[(size_t)(b * NC + c) * DI + d] = ssum;
}

// ---------------------------------------------------------------------------
// scan phase 2: in-place chunk combine (bf16 H); Hend -> Hin
// ---------------------------------------------------------------------------
__global__ void scan_phase2(unsigned short* __restrict__ H, const float* __restrict__ dtsum,
                            const float* __restrict__ At2) {
    int idx = blockIdx.x * 256 + threadIdx.x;
    int b = idx / (DS * DI);
    int r = idx % (DS * DI);
    int n = r / DI, d = r % DI;
    float A2 = At2[n * DI + d];
    float h = 0.f;
    #pragma unroll 4
    for (int c = 0; c < NC; ++c) {
        size_t off = ((size_t)(b * NC + c) * DS + n) * DI + d;
        float He = bf2f(H[off]);
        float P = fexp2(A2 * dtsum[(size_t)(b * NC + c) * DI + d]);
        H[off] = f2bf(h);
        h = P * h + He;
    }
}

// ---------------------------------------------------------------------------
// scan phase 3: parallel correction + gate; y (bf16) over S slots in XZb
// ---------------------------------------------------------------------------
__global__ __launch_bounds__(256)
void scan_phase3(const unsigned short* __restrict__ xactb, const unsigned short* __restrict__ yloc,
                 const float* __restrict__ proj, const float* __restrict__ At2,
                 const float* __restrict__ Dp, const unsigned short* __restrict__ Hin,
                 unsigned short* __restrict__ XZb) {
    const int tid = threadIdx.x;
    const int d = blockIdx.x * 256 + tid;
    const int c = blockIdx.y;
    const int b = blockIdx.z;

    f32x2 A2[DS / 2], Hn2[DS / 2];
    size_t hbase = ((size_t)(b * NC + c) * DS) * DI + d;
    #pragma unroll
    for (int p = 0; p < DS / 2; ++p) {
        A2[p]  = (f32x2){At2[(2 * p) * DI + d], At2[(2 * p + 1) * DI + d]};
        Hn2[p] = (f32x2){bf2f(Hin[hbase + (size_t)(2 * p) * DI]),
                         bf2f(Hin[hbase + (size_t)(2 * p + 1) * DI])};
    }

    const float Dv = Dp[d];
    const int l0 = c * TCH;
    #pragma unroll 2
    for (int l = l0; l < l0 + TCH; ++l) {
        const size_t row = (size_t)(b * LSEQ + l);
        const float* pr = proj + row * 36;
        unsigned short* xzrow = XZb + row * 4096;
        float S  = bf2f(xzrow[d]);
        float yl = bf2f(yloc[row * DI + d]);
        float x  = bf2f(xactb[row * DI + d]);
        float z  = bf2f(xzrow[2048 + d]);
        f32x2 corr2 = (f32x2){0.f, 0.f};
        #pragma unroll
        for (int p = 0; p < DS / 2; ++p) {
            f32x2 t = A2[p] * S;
            f32x2 e2 = (f32x2){fexp2(t.x), fexp2(t.y)};
            corr2 += (f32x2){pr[16 + 2 * p], pr[17 + 2 * p]} * e2 * Hn2[p];
        }
        float y = yl + corr2.x + corr2.y + x * Dv;
        float sz = z / (1.f + __expf(-z));
        xzrow[d] = f2bf(y * sz);
    }
}

// ---------------------------------------------------------------------------
extern "C" void kernel_launch(void* const* d_in, const int* in_sizes, int n_in,
                              void* d_out, int out_size, void* d_ws, size_t ws_size,
                              hipStream_t stream) {
    const float* x      = (const float*)d_in[0];
    const float* W_in   = (const float*)d_in[1];
    const float* conv_w = (const float*)d_in[2];
    const float* conv_b = (const float*)d_in[3];
    const float* W_x    = (const float*)d_in[4];
    const float* A_log  = (const float*)d_in[5];
    const float* Dp     = (const float*)d_in[6];
    const float* W_dt   = (const float*)d_in[7];
    const float* b_dt   = (const float*)d_in[8];
    const float* W_out  = (const float*)d_in[9];
    float* out = (float*)d_out;

    char* ws = (char*)d_ws;
    // workspace layout (bytes), ~112 MiB, no overlays:
    unsigned short* XZb   = (unsigned short*)(ws + 0);           // 32 MiB  [t1..t7]
    unsigned short* XACTB = (unsigned short*)(ws + 33554432);    // 16 MiB  [t2..t6]
    unsigned short* Xb    = (unsigned short*)(ws + 50331648);    // 8 MiB   [t0..t1]
    unsigned short* W_inb = (unsigned short*)(ws + 58720256);    // 8 MiB   [t0..t1]
    unsigned short* Hbuf  = (unsigned short*)(ws + 67108864);    // 16 MiB  [t4..t6]
    unsigned short* YLOC  = (unsigned short*)(ws + 83886080);    // 16 MiB  [t4..t6]
    float* PROJ  = (float*)(ws + 100663296);                     // 0.56 MiB
    float* DTSUM = (float*)(ws + 101711872);                     // 2 MiB
    float* PROJP = (float*)(ws + 103809024);                     // 2.25 MiB
    float* Abuf  = (float*)(ws + 106954752);                     // 128 KiB
    unsigned short* W_outb = (unsigned short*)(ws + 108003328);  // 4 MiB
    unsigned short* Wxb48  = (unsigned short*)(ws + 112197632);  // 192 KiB

    const int M = BATCH * LSEQ;   // 4096

    // t0) converts / prep
    cvt_bf16<<<M * DMODEL / 8 / 256, 256, 0, stream>>>(x, Xb, M * DMODEL / 8);
    cvt_bf16<<<2 * DI * DMODEL / 8 / 256, 256, 0, stream>>>(W_in, W_inb, 2 * DI * DMODEL / 8);
    prep_wx<<<48, 256, 0, stream>>>(W_x, Wxb48);
    prep_A<<<DS * DI / 256, 256, 0, stream>>>(A_log, Abuf);

    // t1) xz = x @ W_in.T -> bf16 XZb (8-phase 256^2 kernel)
    gemm1_8ph<<<256, 512, 0, stream>>>(Xb, W_inb, XZb);

    // t2) depthwise conv + SiLU -> XACTB (bf16)
    conv_silu<<<BATCH * LSEQ * DI / 8 / 256, 256, 0, stream>>>(XZb, conv_w, conv_b, XACTB);

    // t3) proj
    gemm_proj_mfma<<<dim3(M / 64, 4), 256, 0, stream>>>(XACTB, Wxb48, PROJP);
    proj_combine<<<(M * 33 + 255) / 256, 256, 0, stream>>>(PROJP, PROJ);

    // t4-t6) chunked scan
    scan_phase1<<<dim3(DI / 256, NC, BATCH), 256, 0, stream>>>(
        XACTB, PROJ, Abuf, W_dt, b_dt, Hbuf, DTSUM, YLOC, XZb);
    scan_phase2<<<BATCH * DS * DI / 256, 256, 0, stream>>>(Hbuf, DTSUM, Abuf);
    scan_phase3<<<dim3(DI / 256, NC, BATCH), 256, 0, stream>>>(
        XACTB, YLOC, PROJ, Abuf, Dp, Hbuf, XZb);

    // t7) out = y @ W_out.T  (A = y in XZb cols 0..2047, lda = 4096) -- pipelined
    cvt_bf16<<<DMODEL * DI / 8 / 256, 256, 0, stream>>>(W_out, W_outb, DMODEL * DI / 8);
    gemm3_pipe<<<512, 256, 0, stream>>>(XZb, 4096, W_outb, out);
}

// Round 9
// 204.819 us; speedup vs baseline: 1.0380x; 1.0380x over previous
//
#include <hip/hip_runtime.h>
#include <hip/hip_bf16.h>
#include <cstddef>

#define DMODEL 1024
#define DI     2048
#define DS     16
#define LSEQ   2048
#define BATCH  2
#define NC     128           // number of scan chunks
#define TCH    (LSEQ / NC)   // 16 steps per chunk

typedef __attribute__((ext_vector_type(8))) short short8;
typedef __attribute__((ext_vector_type(4))) float f32x4;
typedef __attribute__((ext_vector_type(2))) float f32x2;
typedef __attribute__((ext_vector_type(8))) unsigned short us8;

__device__ __forceinline__ unsigned short f2bf(float f) {
    unsigned int u = __float_as_uint(f);
    unsigned int r = (u + 0x7fff + ((u >> 16) & 1)) >> 16;   // RNE
    return (unsigned short)r;
}
__device__ __forceinline__ float bf2f(unsigned short b) {
    return __uint_as_float(((unsigned int)b) << 16);
}

__device__ __forceinline__ float fexp2(float x) {
#if __has_builtin(__builtin_amdgcn_exp2f)
    return __builtin_amdgcn_exp2f(x);
#else
    return exp2f(x);
#endif
}
__device__ __forceinline__ float flog2(float x) {
#if __has_builtin(__builtin_amdgcn_logf)
    return __builtin_amdgcn_logf(x);
#else
    return log2f(x);
#endif
}

#define LOG2E 1.4426950408889634f
#define RLOG2E 0.6931471805599453f

__device__ __forceinline__ float softplus_f(float v) {
    return (v > 20.f) ? v : flog2(1.f + fexp2(v * LOG2E)) * RLOG2E;
}

__device__ __forceinline__ void gload_lds16(const void* g, void* l) {
    __builtin_amdgcn_global_load_lds(
        (const __attribute__((address_space(1))) unsigned int*)g,
        (__attribute__((address_space(3))) unsigned int*)l, 16, 0, 0);
}

__device__ __forceinline__ void cvt8_store(const float* __restrict__ in,
                                           unsigned short* __restrict__ out, int i) {
    const float4* p = reinterpret_cast<const float4*>(in) + (size_t)i * 2;
    float4 v0 = p[0], v1 = p[1];
    us8 o;
    o[0] = f2bf(v0.x); o[1] = f2bf(v0.y); o[2] = f2bf(v0.z); o[3] = f2bf(v0.w);
    o[4] = f2bf(v1.x); o[5] = f2bf(v1.y); o[6] = f2bf(v1.z); o[7] = f2bf(v1.w);
    *reinterpret_cast<us8*>(out + (size_t)i * 8) = o;
}

// ---------------------------------------------------------------------------
// fused prep: cvt x, W_in, W_out; pad+cvt W_x; A-table  (one launch)
// regions (us8 units): x 524288 | W_in 524288 | W_out 262144 | wx 12288 | A 32768 scalars
// ---------------------------------------------------------------------------
#define PREP_X   524288
#define PREP_WI  (PREP_X + 524288)
#define PREP_WO  (PREP_WI + 262144)
#define PREP_WX  (PREP_WO + 12288)
#define PREP_A   (PREP_WX + 32768)
__global__ void prep_all(const float* __restrict__ x, const float* __restrict__ W_in,
                         const float* __restrict__ W_out, const float* __restrict__ wx,
                         const float* __restrict__ A_log,
                         unsigned short* __restrict__ Xb, unsigned short* __restrict__ W_inb,
                         unsigned short* __restrict__ W_outb, unsigned short* __restrict__ Wxb48,
                         float* __restrict__ At2) {
    int i = blockIdx.x * 256 + threadIdx.x;
    if (i < PREP_X) {
        cvt8_store(x, Xb, i);
    } else if (i < PREP_WI) {
        cvt8_store(W_in, W_inb, i - PREP_X);
    } else if (i < PREP_WO) {
        cvt8_store(W_out, W_outb, i - PREP_WI);
    } else if (i < PREP_WX) {
        int j = i - PREP_WO;
        size_t o = (size_t)j * 8;
        int row = (int)(o >> 11);
        if (row < 33) cvt8_store(wx, Wxb48, j);
        else *reinterpret_cast<us8*>(Wxb48 + o) = (us8)0;
    } else if (i < PREP_A) {
        int j = i - PREP_WX;            // j = n*DI + d
        int n = j / DI, d = j % DI;
        At2[j] = -__expf(A_log[d * DS + n]) * LOG2E;
    }
}

// ---------------------------------------------------------------------------
// GEMM1: 128x256 tile, 8 waves (2Mx4N, wave owns 64x64), BK=32, 2-deep LDS
// dbuf (48 KiB -> 2 blocks/CU at VGPR<=128), XOR swizzle, setprio, bf16 out.
// M=4096, N=4096, K=1024 fixed; grid 512 (32 m x 16 n).
// ---------------------------------------------------------------------------
#define NTK1 32
__global__ __launch_bounds__(512, 4)
void gemm1_2b(const unsigned short* __restrict__ A, const unsigned short* __restrict__ B,
              unsigned short* __restrict__ C) {
    __shared__ unsigned short As[2][128 * 32];   // 2 x 8 KiB
    __shared__ unsigned short Bs[2][256 * 32];   // 2 x 16 KiB

    const int tid = threadIdx.x;
    const int wid = tid >> 6, ln = tid & 63;
    const int wm = wid >> 2, wn = wid & 3;       // wave owns 64x64

    int wg = blockIdx.x;
    wg = (wg & 7) * 64 + (wg >> 3);              // XCD swizzle (512 % 8 == 0)
    const int m0 = (wg >> 4) * 128;
    const int n0 = (wg & 15) * 256;

    const int srow = tid >> 2;                   // 0..127
    const int sun  = tid & 3;
    const int ksrc = ((sun ^ ((srow >> 1) & 3)) * 8);  // same for srow and srow+128

    const int fr = ln & 15;
    const int fku = (ln >> 4);

    f32x4 acc[4][4] = {};

    #define STAGE1(kt, c)                                                                  \
        do {                                                                               \
            gload_lds16(A + (size_t)(m0 + srow) * 1024 + (kt) * 32 + ksrc,                 \
                        &As[c][srow * 32 + sun * 8]);                                      \
            gload_lds16(B + (size_t)(n0 + srow) * 1024 + (kt) * 32 + ksrc,                 \
                        &Bs[c][srow * 32 + sun * 8]);                                      \
            gload_lds16(B + (size_t)(n0 + 128 + srow) * 1024 + (kt) * 32 + ksrc,           \
                        &Bs[c][(128 + srow) * 32 + sun * 8]);                              \
        } while (0)

    STAGE1(0, 0);
    asm volatile("s_waitcnt vmcnt(0)" ::: "memory");
    __builtin_amdgcn_s_barrier();
    __builtin_amdgcn_sched_barrier(0);

    for (int kt = 0; kt < NTK1; ++kt) {
        const int c = kt & 1;
        if (kt + 1 < NTK1) STAGE1(kt + 1, c ^ 1);   // c^1 fully consumed before last barrier

        short8 af[4], bfr[4];
        #pragma unroll
        for (int i = 0; i < 4; ++i) {
            int r = wm * 64 + i * 16 + fr;
            int u = fku ^ ((r >> 1) & 3);
            af[i] = *reinterpret_cast<const short8*>(&As[c][r * 32 + u * 8]);
        }
        #pragma unroll
        for (int j = 0; j < 4; ++j) {
            int r = wn * 64 + j * 16 + fr;
            int u = fku ^ ((r >> 1) & 3);
            bfr[j] = *reinterpret_cast<const short8*>(&Bs[c][r * 32 + u * 8]);
        }
        __builtin_amdgcn_sched_barrier(0);
        __builtin_amdgcn_s_setprio(1);
        #pragma unroll
        for (int i = 0; i < 4; ++i)
            #pragma unroll
            for (int j = 0; j < 4; ++j)
                acc[i][j] = __builtin_amdgcn_mfma_f32_16x16x32_bf16(af[i], bfr[j], acc[i][j], 0, 0, 0);
        __builtin_amdgcn_s_setprio(0);
        __builtin_amdgcn_sched_barrier(0);

        if (kt + 1 < NTK1) asm volatile("s_waitcnt vmcnt(0)" ::: "memory");
        __builtin_amdgcn_s_barrier();
        __builtin_amdgcn_sched_barrier(0);
    }
    #undef STAGE1

    const int cr = (ln >> 4) * 4, cc = ln & 15;
    #pragma unroll
    for (int i = 0; i < 4; ++i) {
        int row = m0 + wm * 64 + i * 16 + cr;
        #pragma unroll
        for (int j = 0; j < 4; ++j) {
            int col = n0 + wn * 64 + j * 16 + cc;
            #pragma unroll
            for (int r = 0; r < 4; ++r)
                C[(size_t)(row + r) * 4096 + col] = f2bf(acc[i][j][r]);
        }
    }
}

// ---------------------------------------------------------------------------
// GEMM3: 128x64 tile, 4 waves (2x2), BK=32, 4-deep pipeline, counted vmcnt,
// k-unit XOR swizzle, f32 out.  M=4096, N=1024, K=2048 fixed; grid 512.
// ---------------------------------------------------------------------------
#define NT3 64
__global__ __launch_bounds__(256, 2)
void gemm3_pipe(const unsigned short* __restrict__ A, int lda,
                const unsigned short* __restrict__ B,
                float* __restrict__ C) {
    __shared__ unsigned short As[4][128 * 32];   // 32 KiB
    __shared__ unsigned short Bs[4][64 * 32];    // 16 KiB

    const int tid = threadIdx.x;
    const int wid = tid >> 6, ln = tid & 63;
    const int wm = wid >> 1, wn = wid & 1;       // wave owns 64x32

    int wg = blockIdx.x;
    wg = (wg & 7) * 64 + (wg >> 3);              // XCD swizzle (512 % 8 == 0)
    const int m0 = (wg >> 4) * 128;
    const int n0 = (wg & 15) * 64;

    const int srow = tid >> 2;                   // 0..63
    const int sun  = tid & 3;
    const int ksrc = ((sun ^ ((srow >> 1) & 3)) * 8);

    const int fr = ln & 15;
    const int fku = (ln >> 4);

    f32x4 acc[4][2] = {};

    #define STAGE3(kt)                                                                     \
        do {                                                                               \
            const int bq_ = (kt) & 3;                                                      \
            gload_lds16(A + (size_t)(m0 + srow) * lda + (kt) * 32 + ksrc,                  \
                        &As[bq_][srow * 32 + sun * 8]);                                    \
            gload_lds16(A + (size_t)(m0 + 64 + srow) * lda + (kt) * 32 + ksrc,             \
                        &As[bq_][(64 + srow) * 32 + sun * 8]);                             \
            gload_lds16(B + (size_t)(n0 + srow) * 2048 + (kt) * 32 + ksrc,                 \
                        &Bs[bq_][srow * 32 + sun * 8]);                                    \
        } while (0)

    STAGE3(0); STAGE3(1); STAGE3(2);
    asm volatile("s_waitcnt vmcnt(6)" ::: "memory");   // K-tile 0 landed
    __builtin_amdgcn_s_barrier();
    __builtin_amdgcn_sched_barrier(0);

    for (int kt = 0; kt < NT3; ++kt) {
        const int bq = kt & 3;
        if (kt + 3 < NT3) STAGE3(kt + 3);

        short8 af[4], bfr[2];
        #pragma unroll
        for (int i = 0; i < 4; ++i) {
            int r = wm * 64 + i * 16 + fr;
            int u = fku ^ ((r >> 1) & 3);
            af[i] = *reinterpret_cast<const short8*>(&As[bq][r * 32 + u * 8]);
        }
        #pragma unroll
        for (int j = 0; j < 2; ++j) {
            int r = wn * 32 + j * 16 + fr;
            int u = fku ^ ((r >> 1) & 3);
            bfr[j] = *reinterpret_cast<const short8*>(&Bs[bq][r * 32 + u * 8]);
        }
        __builtin_amdgcn_sched_barrier(0);
        __builtin_amdgcn_s_setprio(1);
        #pragma unroll
        for (int i = 0; i < 4; ++i)
            #pragma unroll
            for (int j = 0; j < 2; ++j)
                acc[i][j] = __builtin_amdgcn_mfma_f32_16x16x32_bf16(af[i], bfr[j], acc[i][j], 0, 0, 0);
        __builtin_amdgcn_s_setprio(0);
        __builtin_amdgcn_sched_barrier(0);

        if (kt < NT3 - 3)       asm volatile("s_waitcnt vmcnt(6)" ::: "memory");
        else if (kt == NT3 - 3) asm volatile("s_waitcnt vmcnt(3)" ::: "memory");
        else if (kt == NT3 - 2) asm volatile("s_waitcnt vmcnt(0)" ::: "memory");
        __builtin_amdgcn_s_barrier();
        __builtin_amdgcn_sched_barrier(0);
    }
    #undef STAGE3

    const int cr = (ln >> 4) * 4, cc = ln & 15;
    #pragma unroll
    for (int i = 0; i < 4; ++i) {
        int row = m0 + wm * 64 + i * 16 + cr;
        #pragma unroll
        for (int j = 0; j < 2; ++j) {
            int col = n0 + wn * 32 + j * 16 + cc;
            #pragma unroll
            for (int r = 0; r < 4; ++r)
                C[(size_t)(row + r) * 1024 + col] = acc[i][j][r];
        }
    }
}

// ---------------------------------------------------------------------------
// depthwise causal conv (width 4) + bias + SiLU; bf16 in (XZb), bf16 out
// ---------------------------------------------------------------------------
__global__ void conv_silu(const unsigned short* __restrict__ xzb, const float* __restrict__ cw,
                          const float* __restrict__ cb, unsigned short* __restrict__ xactb) {
    int i = blockIdx.x * 256 + threadIdx.x;        // over B*L*DI/8
    if (i >= BATCH * LSEQ * DI / 8) return;
    int d0 = (i % (DI / 8)) * 8;
    int l  = (i / (DI / 8)) % LSEQ;
    int b  = i / ((DI / 8) * LSEQ);

    float4 w[8];
    #pragma unroll
    for (int j = 0; j < 8; ++j)
        w[j] = *reinterpret_cast<const float4*>(cw + (d0 + j) * 4);

    float acc[8];
    #pragma unroll
    for (int j = 0; j < 8; ++j) acc[j] = cb[d0 + j];

    #pragma unroll
    for (int t = 0; t < 4; ++t) {
        int ls = l - 3 + t;
        if (ls >= 0) {
            us8 v = *reinterpret_cast<const us8*>(xzb + (size_t)(b * LSEQ + ls) * 4096 + d0);
            #pragma unroll
            for (int j = 0; j < 8; ++j) {
                float wt = (t == 0) ? w[j].x : (t == 1) ? w[j].y : (t == 2) ? w[j].z : w[j].w;
                acc[j] += bf2f(v[j]) * wt;
            }
        }
    }
    us8 o;
    #pragma unroll
    for (int j = 0; j < 8; ++j) {
        float v = acc[j] / (1.f + __expf(-acc[j]));
        o[j] = f2bf(v);
    }
    *reinterpret_cast<us8*>(xactb + (size_t)i * 8) = o;
}

// ---------------------------------------------------------------------------
// skinny MFMA GEMM for proj: partials -> PROJP[row*144 + kz*36 + col]
// ---------------------------------------------------------------------------
__global__ __launch_bounds__(256)
void gemm_proj_mfma(const unsigned short* __restrict__ Xb, const unsigned short* __restrict__ Wxb,
                    float* __restrict__ projp) {
    __shared__ unsigned short As[64 * 32];
    __shared__ unsigned short Bs[48 * 32];

    const int tid = threadIdx.x;
    const int wv = tid >> 6, ln = tid & 63;
    const int m0 = blockIdx.x * 64;
    const int kz = blockIdx.y;
    const int srow = tid >> 2, skoff = (tid & 3) * 8;
    const int fr = ln & 15, fk = (ln >> 4) * 8;

    f32x4 acc[3] = {};

    const int k0base = kz * 512;
    for (int k0 = k0base; k0 < k0base + 512; k0 += 32) {
        gload_lds16(Xb + (size_t)(m0 + srow) * DI + k0 + skoff, &As[wv * 512]);
        if (wv < 3)
            gload_lds16(Wxb + (size_t)srow * DI + k0 + skoff, &Bs[wv * 512]);
        __syncthreads();

        short8 af = *reinterpret_cast<const short8*>(&As[(wv * 16 + fr) * 32 + fk]);
        #pragma unroll
        for (int j = 0; j < 3; ++j) {
            short8 bf_ = *reinterpret_cast<const short8*>(&Bs[(j * 16 + fr) * 32 + fk]);
            acc[j] = __builtin_amdgcn_mfma_f32_16x16x32_bf16(af, bf_, acc[j], 0, 0, 0);
        }
        __syncthreads();
    }

    const int cr = (ln >> 4) * 4, cc = ln & 15;
    #pragma unroll
    for (int j = 0; j < 3; ++j) {
        int col = j * 16 + cc;
        if (col < 33) {
            #pragma unroll
            for (int r = 0; r < 4; ++r) {
                int row = m0 + wv * 16 + cr + r;
                projp[(size_t)row * 144 + kz * 36 + col] = acc[j][r];
            }
        }
    }
}

// combine 4 K-split partials
__global__ void proj_combine(const float* __restrict__ projp, float* __restrict__ proj) {
    int idx = blockIdx.x * 256 + threadIdx.x;
    if (idx >= BATCH * LSEQ * 33) return;
    int row = idx / 33, col = idx % 33;
    float s = 0.f;
    #pragma unroll
    for (int kz = 0; kz < 4; ++kz)
        s += projp[(size_t)row * 144 + kz * 36 + col];
    proj[(size_t)row * 36 + col] = s;
}

// ---------------------------------------------------------------------------
// scan phase 1: local scan (h0=0); y_local (bf16), S prefix (bf16 into XZb
// x-cols), Hend (bf16), dtsum (f32)
// ---------------------------------------------------------------------------
__global__ __launch_bounds__(256)
void scan_phase1(const unsigned short* __restrict__ xactb, const float* __restrict__ proj,
                 const float* __restrict__ At2, const float* __restrict__ W_dt,
                 const float* __restrict__ b_dt, unsigned short* __restrict__ Hend,
                 float* __restrict__ dtsum, unsigned short* __restrict__ yloc,
                 unsigned short* __restrict__ XZb) {
    const int d = blockIdx.x * 256 + threadIdx.x;
    const int c = blockIdx.y;
    const int b = blockIdx.z;

    f32x2 A2[DS / 2], h2[DS / 2];
    #pragma unroll
    for (int p = 0; p < DS / 2; ++p) {
        A2[p] = (f32x2){At2[(2 * p) * DI + d], At2[(2 * p + 1) * DI + d]};
        h2[p] = (f32x2){0.f, 0.f};
    }
    const float wdt = W_dt[d], bdt = b_dt[d];
    float ssum = 0.f;

    const int l0 = c * TCH;
    #pragma unroll 2
    for (int l = l0; l < l0 + TCH; ++l) {
        const size_t row = (size_t)(b * LSEQ + l);
        const float* pr = proj + row * 36;
        float dt = softplus_f(pr[32] * wdt + bdt);
        ssum += dt;
        XZb[row * 4096 + d] = f2bf(ssum);
        float x = bf2f(xactb[row * DI + d]);
        float xdt = x * dt;
        f32x2 xdt2 = (f32x2){xdt, xdt};
        f32x2 y2 = (f32x2){0.f, 0.f};
        #pragma unroll
        for (int p = 0; p < DS / 2; ++p) {
            f32x2 t = A2[p] * dt;
            f32x2 e2 = (f32x2){fexp2(t.x), fexp2(t.y)};
            h2[p] = e2 * h2[p] + xdt2 * (f32x2){pr[2 * p], pr[2 * p + 1]};
            y2 += h2[p] * (f32x2){pr[16 + 2 * p], pr[17 + 2 * p]};
        }
        yloc[row * DI + d] = f2bf(y2.x + y2.y);
    }
    size_t base = ((size_t)(b * NC + c) * DS) * DI + d;
    #pragma unroll
    for (int p = 0; p < DS / 2; ++p) {
        Hend[base + (size_t)(2 * p) * DI]     = f2bf(h2[p].x);
        Hend[base + (size_t)(2 * p + 1) * DI] = f2bf(h2[p].y);
    }
    dtsum[(size_t)(b * NC + c) * DI + d] = ssum;
}

// ---------------------------------------------------------------------------
// scan phase 2: in-place chunk combine (bf16 H); Hend -> Hin
// ---------------------------------------------------------------------------
__global__ void scan_phase2(unsigned short* __restrict__ H, const float* __restrict__ dtsum,
                            const float* __restrict__ At2) {
    int idx = blockIdx.x * 256 + threadIdx.x;
    int b = idx / (DS * DI);
    int r = idx % (DS * DI);
    int n = r / DI, d = r % DI;
    float A2 = At2[n * DI + d];
    float h = 0.f;
    #pragma unroll 4
    for (int c = 0; c < NC; ++c) {
        size_t off = ((size_t)(b * NC + c) * DS + n) * DI + d;
        float He = bf2f(H[off]);
        float P = fexp2(A2 * dtsum[(size_t)(b * NC + c) * DI + d]);
        H[off] = f2bf(h);
        h = P * h + He;
    }
}

// ---------------------------------------------------------------------------
// scan phase 3: parallel correction + gate; y (bf16) over S slots in XZb
// ---------------------------------------------------------------------------
__global__ __launch_bounds__(256)
void scan_phase3(const unsigned short* __restrict__ xactb, const unsigned short* __restrict__ yloc,
                 const float* __restrict__ proj, const float* __restrict__ At2,
                 const float* __restrict__ Dp, const unsigned short* __restrict__ Hin,
                 unsigned short* __restrict__ XZb) {
    const int tid = threadIdx.x;
    const int d = blockIdx.x * 256 + tid;
    const int c = blockIdx.y;
    const int b = blockIdx.z;

    f32x2 A2[DS / 2], Hn2[DS / 2];
    size_t hbase = ((size_t)(b * NC + c) * DS) * DI + d;
    #pragma unroll
    for (int p = 0; p < DS / 2; ++p) {
        A2[p]  = (f32x2){At2[(2 * p) * DI + d], At2[(2 * p + 1) * DI + d]};
        Hn2[p] = (f32x2){bf2f(Hin[hbase + (size_t)(2 * p) * DI]),
                         bf2f(Hin[hbase + (size_t)(2 * p + 1) * DI])};
    }

    const float Dv = Dp[d];
    const int l0 = c * TCH;
    #pragma unroll 2
    for (int l = l0; l < l0 + TCH; ++l) {
        const size_t row = (size_t)(b * LSEQ + l);
        const float* pr = proj + row * 36;
        unsigned short* xzrow = XZb + row * 4096;
        float S  = bf2f(xzrow[d]);
        float yl = bf2f(yloc[row * DI + d]);
        float x  = bf2f(xactb[row * DI + d]);
        float z  = bf2f(xzrow[2048 + d]);
        f32x2 corr2 = (f32x2){0.f, 0.f};
        #pragma unroll
        for (int p = 0; p < DS / 2; ++p) {
            f32x2 t = A2[p] * S;
            f32x2 e2 = (f32x2){fexp2(t.x), fexp2(t.y)};
            corr2 += (f32x2){pr[16 + 2 * p], pr[17 + 2 * p]} * e2 * Hn2[p];
        }
        float y = yl + corr2.x + corr2.y + x * Dv;
        float sz = z / (1.f + __expf(-z));
        xzrow[d] = f2bf(y * sz);
    }
}

// ---------------------------------------------------------------------------
extern "C" void kernel_launch(void* const* d_in, const int* in_sizes, int n_in,
                              void* d_out, int out_size, void* d_ws, size_t ws_size,
                              hipStream_t stream) {
    const float* x      = (const float*)d_in[0];
    const float* W_in   = (const float*)d_in[1];
    const float* conv_w = (const float*)d_in[2];
    const float* conv_b = (const float*)d_in[3];
    const float* W_x    = (const float*)d_in[4];
    const float* A_log  = (const float*)d_in[5];
    const float* Dp     = (const float*)d_in[6];
    const float* W_dt   = (const float*)d_in[7];
    const float* b_dt   = (const float*)d_in[8];
    const float* W_out  = (const float*)d_in[9];
    float* out = (float*)d_out;

    char* ws = (char*)d_ws;
    // workspace layout (bytes), ~112 MiB, no overlays:
    unsigned short* XZb   = (unsigned short*)(ws + 0);           // 32 MiB  [t1..t7]
    unsigned short* XACTB = (unsigned short*)(ws + 33554432);    // 16 MiB  [t2..t6]
    unsigned short* Xb    = (unsigned short*)(ws + 50331648);    // 8 MiB   [t0..t1]
    unsigned short* W_inb = (unsigned short*)(ws + 58720256);    // 8 MiB   [t0..t1]
    unsigned short* Hbuf  = (unsigned short*)(ws + 67108864);    // 16 MiB  [t4..t6]
    unsigned short* YLOC  = (unsigned short*)(ws + 83886080);    // 16 MiB  [t4..t6]
    float* PROJ  = (float*)(ws + 100663296);                     // 0.56 MiB
    float* DTSUM = (float*)(ws + 101711872);                     // 2 MiB
    float* PROJP = (float*)(ws + 103809024);                     // 2.25 MiB
    float* Abuf  = (float*)(ws + 106954752);                     // 128 KiB
    unsigned short* W_outb = (unsigned short*)(ws + 108003328);  // 4 MiB
    unsigned short* Wxb48  = (unsigned short*)(ws + 112197632);  // 192 KiB

    const int M = BATCH * LSEQ;   // 4096

    // t0) fused converts / prep (one launch)
    prep_all<<<(PREP_A + 255) / 256, 256, 0, stream>>>(
        x, W_in, W_out, W_x, A_log, Xb, W_inb, W_outb, Wxb48, Abuf);

    // t1) xz = x @ W_in.T -> bf16 XZb (128x256, 2 blocks/CU)
    gemm1_2b<<<512, 512, 0, stream>>>(Xb, W_inb, XZb);

    // t2) depthwise conv + SiLU -> XACTB (bf16)
    conv_silu<<<BATCH * LSEQ * DI / 8 / 256, 256, 0, stream>>>(XZb, conv_w, conv_b, XACTB);

    // t3) proj
    gemm_proj_mfma<<<dim3(M / 64, 4), 256, 0, stream>>>(XACTB, Wxb48, PROJP);
    proj_combine<<<(M * 33 + 255) / 256, 256, 0, stream>>>(PROJP, PROJ);

    // t4-t6) chunked scan
    scan_phase1<<<dim3(DI / 256, NC, BATCH), 256, 0, stream>>>(
        XACTB, PROJ, Abuf, W_dt, b_dt, Hbuf, DTSUM, YLOC, XZb);
    scan_phase2<<<BATCH * DS * DI / 256, 256, 0, stream>>>(Hbuf, DTSUM, Abuf);
    scan_phase3<<<dim3(DI / 256, NC, BATCH), 256, 0, stream>>>(
        XACTB, YLOC, PROJ, Abuf, Dp, Hbuf, XZb);

    // t7) out = y @ W_out.T  (A = y in XZb cols 0..2047, lda = 4096)
    gemm3_pipe<<<512, 256, 0, stream>>>(XZb, 4096, W_outb, out);
}

// Round 10
// 201.958 us; speedup vs baseline: 1.0527x; 1.0142x over previous
//
#include <hip/hip_runtime.h>
#include <hip/hip_bf16.h>
#include <cstddef>

#define DMODEL 1024
#define DI     2048
#define DS     16
#define LSEQ   2048
#define BATCH  2
#define NC     128           // number of scan chunks
#define TCH    (LSEQ / NC)   // 16 steps per chunk

typedef __attribute__((ext_vector_type(8))) short short8;
typedef __attribute__((ext_vector_type(4))) float f32x4;
typedef __attribute__((ext_vector_type(2))) float f32x2;
typedef __attribute__((ext_vector_type(8))) unsigned short us8;

__device__ __forceinline__ unsigned short f2bf(float f) {
    unsigned int u = __float_as_uint(f);
    unsigned int r = (u + 0x7fff + ((u >> 16) & 1)) >> 16;   // RNE
    return (unsigned short)r;
}
__device__ __forceinline__ float bf2f(unsigned short b) {
    return __uint_as_float(((unsigned int)b) << 16);
}

__device__ __forceinline__ float fexp2(float x) {
#if __has_builtin(__builtin_amdgcn_exp2f)
    return __builtin_amdgcn_exp2f(x);
#else
    return exp2f(x);
#endif
}
__device__ __forceinline__ float flog2(float x) {
#if __has_builtin(__builtin_amdgcn_logf)
    return __builtin_amdgcn_logf(x);
#else
    return log2f(x);
#endif
}

#define LOG2E 1.4426950408889634f
#define RLOG2E 0.6931471805599453f

__device__ __forceinline__ float softplus_f(float v) {
    return (v > 20.f) ? v : flog2(1.f + fexp2(v * LOG2E)) * RLOG2E;
}

__device__ __forceinline__ void gload_lds16(const void* g, void* l) {
    __builtin_amdgcn_global_load_lds(
        (const __attribute__((address_space(1))) unsigned int*)g,
        (__attribute__((address_space(3))) unsigned int*)l, 16, 0, 0);
}

__device__ __forceinline__ void cvt8_store(const float* __restrict__ in,
                                           unsigned short* __restrict__ out, int i) {
    const float4* p = reinterpret_cast<const float4*>(in) + (size_t)i * 2;
    float4 v0 = p[0], v1 = p[1];
    us8 o;
    o[0] = f2bf(v0.x); o[1] = f2bf(v0.y); o[2] = f2bf(v0.z); o[3] = f2bf(v0.w);
    o[4] = f2bf(v1.x); o[5] = f2bf(v1.y); o[6] = f2bf(v1.z); o[7] = f2bf(v1.w);
    *reinterpret_cast<us8*>(out + (size_t)i * 8) = o;
}

// ---------------------------------------------------------------------------
// fused prep: cvt x, W_in, W_out; pad+cvt W_x; A-table  (one launch)
// ---------------------------------------------------------------------------
#define PREP_X   524288
#define PREP_WI  (PREP_X + 524288)
#define PREP_WO  (PREP_WI + 262144)
#define PREP_WX  (PREP_WO + 12288)
#define PREP_A   (PREP_WX + 32768)
__global__ void prep_all(const float* __restrict__ x, const float* __restrict__ W_in,
                         const float* __restrict__ W_out, const float* __restrict__ wx,
                         const float* __restrict__ A_log,
                         unsigned short* __restrict__ Xb, unsigned short* __restrict__ W_inb,
                         unsigned short* __restrict__ W_outb, unsigned short* __restrict__ Wxb48,
                         float* __restrict__ At2) {
    int i = blockIdx.x * 256 + threadIdx.x;
    if (i < PREP_X) {
        cvt8_store(x, Xb, i);
    } else if (i < PREP_WI) {
        cvt8_store(W_in, W_inb, i - PREP_X);
    } else if (i < PREP_WO) {
        cvt8_store(W_out, W_outb, i - PREP_WI);
    } else if (i < PREP_WX) {
        int j = i - PREP_WO;
        size_t o = (size_t)j * 8;
        int row = (int)(o >> 11);
        if (row < 33) cvt8_store(wx, Wxb48, j);
        else *reinterpret_cast<us8*>(Wxb48 + o) = (us8)0;
    } else if (i < PREP_A) {
        int j = i - PREP_WX;            // j = n*DI + d
        int n = j / DI, d = j % DI;
        At2[j] = -__expf(A_log[d * DS + n]) * LOG2E;
    }
}

// ---------------------------------------------------------------------------
// GEMM1: 128x256 tile, 8 waves (2Mx4N, wave owns 64x64), BK=32, 3-deep LDS
// ring (72 KiB -> 2 blocks/CU), COUNTED vmcnt(3), XOR swizzle, setprio,
// bf16 out.  M=4096, N=4096, K=1024 fixed; grid 512 (32 m x 16 n).
// ---------------------------------------------------------------------------
#define NTK1 32
__global__ __launch_bounds__(512, 4)
void gemm1_3d(const unsigned short* __restrict__ A, const unsigned short* __restrict__ B,
              unsigned short* __restrict__ C) {
    __shared__ unsigned short As[3][128 * 32];   // 3 x 8 KiB
    __shared__ unsigned short Bs[3][256 * 32];   // 3 x 16 KiB

    const int tid = threadIdx.x;
    const int wid = tid >> 6, ln = tid & 63;
    const int wm = wid >> 2, wn = wid & 3;       // wave owns 64x64

    int wg = blockIdx.x;
    wg = (wg & 7) * 64 + (wg >> 3);              // XCD swizzle (512 % 8 == 0)
    const int m0 = (wg >> 4) * 128;
    const int n0 = (wg & 15) * 256;

    const int srow = tid >> 2;                   // 0..127
    const int sun  = tid & 3;
    const int ksrc = ((sun ^ ((srow >> 1) & 3)) * 8);  // same for srow and srow+128

    const int fr = ln & 15;
    const int fku = (ln >> 4);

    f32x4 acc[4][4] = {};

    #define STAGE1(kt, c)                                                                  \
        do {                                                                               \
            gload_lds16(A + (size_t)(m0 + srow) * 1024 + (kt) * 32 + ksrc,                 \
                        &As[c][srow * 32 + sun * 8]);                                      \
            gload_lds16(B + (size_t)(n0 + srow) * 1024 + (kt) * 32 + ksrc,                 \
                        &Bs[c][srow * 32 + sun * 8]);                                      \
            gload_lds16(B + (size_t)(n0 + 128 + srow) * 1024 + (kt) * 32 + ksrc,           \
                        &Bs[c][(128 + srow) * 32 + sun * 8]);                              \
        } while (0)

    STAGE1(0, 0);
    STAGE1(1, 1);
    asm volatile("s_waitcnt vmcnt(3)" ::: "memory");   // tile0 landed; tile1 in flight
    __builtin_amdgcn_s_barrier();
    __builtin_amdgcn_sched_barrier(0);

    int c = 0, cn = 2;                            // compute buf, next stage buf
    for (int kt = 0; kt < NTK1; ++kt) {
        if (kt + 2 < NTK1) STAGE1(kt + 2, cn);    // buf cn == (kt+2)%3: read-done at kt-1

        short8 af[4], bfr[4];
        #pragma unroll
        for (int i = 0; i < 4; ++i) {
            int r = wm * 64 + i * 16 + fr;
            int u = fku ^ ((r >> 1) & 3);
            af[i] = *reinterpret_cast<const short8*>(&As[c][r * 32 + u * 8]);
        }
        #pragma unroll
        for (int j = 0; j < 4; ++j) {
            int r = wn * 64 + j * 16 + fr;
            int u = fku ^ ((r >> 1) & 3);
            bfr[j] = *reinterpret_cast<const short8*>(&Bs[c][r * 32 + u * 8]);
        }
        __builtin_amdgcn_sched_barrier(0);
        __builtin_amdgcn_s_setprio(1);
        #pragma unroll
        for (int i = 0; i < 4; ++i)
            #pragma unroll
            for (int j = 0; j < 4; ++j)
                acc[i][j] = __builtin_amdgcn_mfma_f32_16x16x32_bf16(af[i], bfr[j], acc[i][j], 0, 0, 0);
        __builtin_amdgcn_s_setprio(0);
        __builtin_amdgcn_sched_barrier(0);

        if (kt < NTK1 - 2)       asm volatile("s_waitcnt vmcnt(3)" ::: "memory");
        else if (kt == NTK1 - 2) asm volatile("s_waitcnt vmcnt(0)" ::: "memory");
        __builtin_amdgcn_s_barrier();
        __builtin_amdgcn_sched_barrier(0);

        c = (c == 2) ? 0 : c + 1;
        cn = (cn == 2) ? 0 : cn + 1;
    }
    #undef STAGE1

    const int cr = (ln >> 4) * 4, cc = ln & 15;
    #pragma unroll
    for (int i = 0; i < 4; ++i) {
        int row = m0 + wm * 64 + i * 16 + cr;
        #pragma unroll
        for (int j = 0; j < 4; ++j) {
            int col = n0 + wn * 64 + j * 16 + cc;
            #pragma unroll
            for (int r = 0; r < 4; ++r)
                C[(size_t)(row + r) * 4096 + col] = f2bf(acc[i][j][r]);
        }
    }
}

// ---------------------------------------------------------------------------
// GEMM3: 128x64 tile, 4 waves (2x2), BK=32, 4-deep pipeline, counted vmcnt,
// k-unit XOR swizzle, f32 out.  M=4096, N=1024, K=2048 fixed; grid 512.
// ---------------------------------------------------------------------------
#define NT3 64
__global__ __launch_bounds__(256, 2)
void gemm3_pipe(const unsigned short* __restrict__ A, int lda,
                const unsigned short* __restrict__ B,
                float* __restrict__ C) {
    __shared__ unsigned short As[4][128 * 32];   // 32 KiB
    __shared__ unsigned short Bs[4][64 * 32];    // 16 KiB

    const int tid = threadIdx.x;
    const int wid = tid >> 6, ln = tid & 63;
    const int wm = wid >> 1, wn = wid & 1;       // wave owns 64x32

    int wg = blockIdx.x;
    wg = (wg & 7) * 64 + (wg >> 3);              // XCD swizzle (512 % 8 == 0)
    const int m0 = (wg >> 4) * 128;
    const int n0 = (wg & 15) * 64;

    const int srow = tid >> 2;                   // 0..63
    const int sun  = tid & 3;
    const int ksrc = ((sun ^ ((srow >> 1) & 3)) * 8);

    const int fr = ln & 15;
    const int fku = (ln >> 4);

    f32x4 acc[4][2] = {};

    #define STAGE3(kt)                                                                     \
        do {                                                                               \
            const int bq_ = (kt) & 3;                                                      \
            gload_lds16(A + (size_t)(m0 + srow) * lda + (kt) * 32 + ksrc,                  \
                        &As[bq_][srow * 32 + sun * 8]);                                    \
            gload_lds16(A + (size_t)(m0 + 64 + srow) * lda + (kt) * 32 + ksrc,             \
                        &As[bq_][(64 + srow) * 32 + sun * 8]);                             \
            gload_lds16(B + (size_t)(n0 + srow) * 2048 + (kt) * 32 + ksrc,                 \
                        &Bs[bq_][srow * 32 + sun * 8]);                                    \
        } while (0)

    STAGE3(0); STAGE3(1); STAGE3(2);
    asm volatile("s_waitcnt vmcnt(6)" ::: "memory");   // K-tile 0 landed
    __builtin_amdgcn_s_barrier();
    __builtin_amdgcn_sched_barrier(0);

    for (int kt = 0; kt < NT3; ++kt) {
        const int bq = kt & 3;
        if (kt + 3 < NT3) STAGE3(kt + 3);

        short8 af[4], bfr[2];
        #pragma unroll
        for (int i = 0; i < 4; ++i) {
            int r = wm * 64 + i * 16 + fr;
            int u = fku ^ ((r >> 1) & 3);
            af[i] = *reinterpret_cast<const short8*>(&As[bq][r * 32 + u * 8]);
        }
        #pragma unroll
        for (int j = 0; j < 2; ++j) {
            int r = wn * 32 + j * 16 + fr;
            int u = fku ^ ((r >> 1) & 3);
            bfr[j] = *reinterpret_cast<const short8*>(&Bs[bq][r * 32 + u * 8]);
        }
        __builtin_amdgcn_sched_barrier(0);
        __builtin_amdgcn_s_setprio(1);
        #pragma unroll
        for (int i = 0; i < 4; ++i)
            #pragma unroll
            for (int j = 0; j < 2; ++j)
                acc[i][j] = __builtin_amdgcn_mfma_f32_16x16x32_bf16(af[i], bfr[j], acc[i][j], 0, 0, 0);
        __builtin_amdgcn_s_setprio(0);
        __builtin_amdgcn_sched_barrier(0);

        if (kt < NT3 - 3)       asm volatile("s_waitcnt vmcnt(6)" ::: "memory");
        else if (kt == NT3 - 3) asm volatile("s_waitcnt vmcnt(3)" ::: "memory");
        else if (kt == NT3 - 2) asm volatile("s_waitcnt vmcnt(0)" ::: "memory");
        __builtin_amdgcn_s_barrier();
        __builtin_amdgcn_sched_barrier(0);
    }
    #undef STAGE3

    const int cr = (ln >> 4) * 4, cc = ln & 15;
    #pragma unroll
    for (int i = 0; i < 4; ++i) {
        int row = m0 + wm * 64 + i * 16 + cr;
        #pragma unroll
        for (int j = 0; j < 2; ++j) {
            int col = n0 + wn * 32 + j * 16 + cc;
            #pragma unroll
            for (int r = 0; r < 4; ++r)
                C[(size_t)(row + r) * 1024 + col] = acc[i][j][r];
        }
    }
}

// ---------------------------------------------------------------------------
// depthwise causal conv (width 4) + bias + SiLU; bf16 in (XZb), bf16 out
// ---------------------------------------------------------------------------
__global__ void conv_silu(const unsigned short* __restrict__ xzb, const float* __restrict__ cw,
                          const float* __restrict__ cb, unsigned short* __restrict__ xactb) {
    int i = blockIdx.x * 256 + threadIdx.x;        // over B*L*DI/8
    if (i >= BATCH * LSEQ * DI / 8) return;
    int d0 = (i % (DI / 8)) * 8;
    int l  = (i / (DI / 8)) % LSEQ;
    int b  = i / ((DI / 8) * LSEQ);

    float4 w[8];
    #pragma unroll
    for (int j = 0; j < 8; ++j)
        w[j] = *reinterpret_cast<const float4*>(cw + (d0 + j) * 4);

    float acc[8];
    #pragma unroll
    for (int j = 0; j < 8; ++j) acc[j] = cb[d0 + j];

    #pragma unroll
    for (int t = 0; t < 4; ++t) {
        int ls = l - 3 + t;
        if (ls >= 0) {
            us8 v = *reinterpret_cast<const us8*>(xzb + (size_t)(b * LSEQ + ls) * 4096 + d0);
            #pragma unroll
            for (int j = 0; j < 8; ++j) {
                float wt = (t == 0) ? w[j].x : (t == 1) ? w[j].y : (t == 2) ? w[j].z : w[j].w;
                acc[j] += bf2f(v[j]) * wt;
            }
        }
    }
    us8 o;
    #pragma unroll
    for (int j = 0; j < 8; ++j) {
        float v = acc[j] / (1.f + __expf(-acc[j]));
        o[j] = f2bf(v);
    }
    *reinterpret_cast<us8*>(xactb + (size_t)i * 8) = o;
}

// ---------------------------------------------------------------------------
// skinny MFMA GEMM for proj: partials -> PROJP[row*144 + kz*36 + col]
// ---------------------------------------------------------------------------
__global__ __launch_bounds__(256)
void gemm_proj_mfma(const unsigned short* __restrict__ Xb, const unsigned short* __restrict__ Wxb,
                    float* __restrict__ projp) {
    __shared__ unsigned short As[64 * 32];
    __shared__ unsigned short Bs[48 * 32];

    const int tid = threadIdx.x;
    const int wv = tid >> 6, ln = tid & 63;
    const int m0 = blockIdx.x * 64;
    const int kz = blockIdx.y;
    const int srow = tid >> 2, skoff = (tid & 3) * 8;
    const int fr = ln & 15, fk = (ln >> 4) * 8;

    f32x4 acc[3] = {};

    const int k0base = kz * 512;
    for (int k0 = k0base; k0 < k0base + 512; k0 += 32) {
        gload_lds16(Xb + (size_t)(m0 + srow) * DI + k0 + skoff, &As[wv * 512]);
        if (wv < 3)
            gload_lds16(Wxb + (size_t)srow * DI + k0 + skoff, &Bs[wv * 512]);
        __syncthreads();

        short8 af = *reinterpret_cast<const short8*>(&As[(wv * 16 + fr) * 32 + fk]);
        #pragma unroll
        for (int j = 0; j < 3; ++j) {
            short8 bf_ = *reinterpret_cast<const short8*>(&Bs[(j * 16 + fr) * 32 + fk]);
            acc[j] = __builtin_amdgcn_mfma_f32_16x16x32_bf16(af, bf_, acc[j], 0, 0, 0);
        }
        __syncthreads();
    }

    const int cr = (ln >> 4) * 4, cc = ln & 15;
    #pragma unroll
    for (int j = 0; j < 3; ++j) {
        int col = j * 16 + cc;
        if (col < 33) {
            #pragma unroll
            for (int r = 0; r < 4; ++r) {
                int row = m0 + wv * 16 + cr + r;
                projp[(size_t)row * 144 + kz * 36 + col] = acc[j][r];
            }
        }
    }
}

// combine 4 K-split partials
__global__ void proj_combine(const float* __restrict__ projp, float* __restrict__ proj) {
    int idx = blockIdx.x * 256 + threadIdx.x;
    if (idx >= BATCH * LSEQ * 33) return;
    int row = idx / 33, col = idx % 33;
    float s = 0.f;
    #pragma unroll
    for (int kz = 0; kz < 4; ++kz)
        s += projp[(size_t)row * 144 + kz * 36 + col];
    proj[(size_t)row * 36 + col] = s;
}

// ---------------------------------------------------------------------------
// scan phase 1: local scan (h0=0); y_local + x*D (bf16), S prefix (bf16 into
// XZb x-cols), Hend (bf16), dtsum (f32)
// ---------------------------------------------------------------------------
__global__ __launch_bounds__(256)
void scan_phase1(const unsigned short* __restrict__ xactb, const float* __restrict__ proj,
                 const float* __restrict__ At2, const float* __restrict__ W_dt,
                 const float* __restrict__ b_dt, const float* __restrict__ Dp,
                 unsigned short* __restrict__ Hend,
                 float* __restrict__ dtsum, unsigned short* __restrict__ yloc,
                 unsigned short* __restrict__ XZb) {
    const int d = blockIdx.x * 256 + threadIdx.x;
    const int c = blockIdx.y;
    const int b = blockIdx.z;

    f32x2 A2[DS / 2], h2[DS / 2];
    #pragma unroll
    for (int p = 0; p < DS / 2; ++p) {
        A2[p] = (f32x2){At2[(2 * p) * DI + d], At2[(2 * p + 1) * DI + d]};
        h2[p] = (f32x2){0.f, 0.f};
    }
    const float wdt = W_dt[d], bdt = b_dt[d], Dv = Dp[d];
    float ssum = 0.f;

    const int l0 = c * TCH;
    #pragma unroll 2
    for (int l = l0; l < l0 + TCH; ++l) {
        const size_t row = (size_t)(b * LSEQ + l);
        const float* pr = proj + row * 36;
        float dt = softplus_f(pr[32] * wdt + bdt);
        ssum += dt;
        XZb[row * 4096 + d] = f2bf(ssum);
        float x = bf2f(xactb[row * DI + d]);
        float xdt = x * dt;
        f32x2 xdt2 = (f32x2){xdt, xdt};
        f32x2 y2 = (f32x2){0.f, 0.f};
        #pragma unroll
        for (int p = 0; p < DS / 2; ++p) {
            f32x2 t = A2[p] * dt;
            f32x2 e2 = (f32x2){fexp2(t.x), fexp2(t.y)};
            h2[p] = e2 * h2[p] + xdt2 * (f32x2){pr[2 * p], pr[2 * p + 1]};
            y2 += h2[p] * (f32x2){pr[16 + 2 * p], pr[17 + 2 * p]};
        }
        yloc[row * DI + d] = f2bf(y2.x + y2.y + x * Dv);   // x*D folded in
    }
    size_t base = ((size_t)(b * NC + c) * DS) * DI + d;
    #pragma unroll
    for (int p = 0; p < DS / 2; ++p) {
        Hend[base + (size_t)(2 * p) * DI]     = f2bf(h2[p].x);
        Hend[base + (size_t)(2 * p + 1) * DI] = f2bf(h2[p].y);
    }
    dtsum[(size_t)(b * NC + c) * DI + d] = ssum;
}

// ---------------------------------------------------------------------------
// scan phase 2: in-place chunk combine (bf16 H); Hend -> Hin
// ---------------------------------------------------------------------------
__global__ void scan_phase2(unsigned short* __restrict__ H, const float* __restrict__ dtsum,
                            const float* __restrict__ At2) {
    int idx = blockIdx.x * 256 + threadIdx.x;
    int b = idx / (DS * DI);
    int r = idx % (DS * DI);
    int n = r / DI, d = r % DI;
    float A2 = At2[n * DI + d];
    float h = 0.f;
    #pragma unroll 4
    for (int c = 0; c < NC; ++c) {
        size_t off = ((size_t)(b * NC + c) * DS + n) * DI + d;
        float He = bf2f(H[off]);
        float P = fexp2(A2 * dtsum[(size_t)(b * NC + c) * DI + d]);
        H[off] = f2bf(h);
        h = P * h + He;
    }
}

// ---------------------------------------------------------------------------
// scan phase 3: parallel correction + gate; y (bf16) over S slots in XZb
// (x*D already folded into yloc by phase 1 -> no xactb read here)
// ---------------------------------------------------------------------------
__global__ __launch_bounds__(256)
void scan_phase3(const unsigned short* __restrict__ yloc,
                 const float* __restrict__ proj, const float* __restrict__ At2,
                 const unsigned short* __restrict__ Hin,
                 unsigned short* __restrict__ XZb) {
    const int tid = threadIdx.x;
    const int d = blockIdx.x * 256 + tid;
    const int c = blockIdx.y;
    const int b = blockIdx.z;

    f32x2 A2[DS / 2], Hn2[DS / 2];
    size_t hbase = ((size_t)(b * NC + c) * DS) * DI + d;
    #pragma unroll
    for (int p = 0; p < DS / 2; ++p) {
        A2[p]  = (f32x2){At2[(2 * p) * DI + d], At2[(2 * p + 1) * DI + d]};
        Hn2[p] = (f32x2){bf2f(Hin[hbase + (size_t)(2 * p) * DI]),
                         bf2f(Hin[hbase + (size_t)(2 * p + 1) * DI])};
    }

    const int l0 = c * TCH;
    #pragma unroll 2
    for (int l = l0; l < l0 + TCH; ++l) {
        const size_t row = (size_t)(b * LSEQ + l);
        const float* pr = proj + row * 36;
        unsigned short* xzrow = XZb + row * 4096;
        float S  = bf2f(xzrow[d]);
        float yl = bf2f(yloc[row * DI + d]);
        float z  = bf2f(xzrow[2048 + d]);
        f32x2 corr2 = (f32x2){0.f, 0.f};
        #pragma unroll
        for (int p = 0; p < DS / 2; ++p) {
            f32x2 t = A2[p] * S;
            f32x2 e2 = (f32x2){fexp2(t.x), fexp2(t.y)};
            corr2 += (f32x2){pr[16 + 2 * p], pr[17 + 2 * p]} * e2 * Hn2[p];
        }
        float y = yl + corr2.x + corr2.y;
        float sz = z / (1.f + __expf(-z));
        xzrow[d] = f2bf(y * sz);
    }
}

// ---------------------------------------------------------------------------
extern "C" void kernel_launch(void* const* d_in, const int* in_sizes, int n_in,
                              void* d_out, int out_size, void* d_ws, size_t ws_size,
                              hipStream_t stream) {
    const float* x      = (const float*)d_in[0];
    const float* W_in   = (const float*)d_in[1];
    const float* conv_w = (const float*)d_in[2];
    const float* conv_b = (const float*)d_in[3];
    const float* W_x    = (const float*)d_in[4];
    const float* A_log  = (const float*)d_in[5];
    const float* Dp     = (const float*)d_in[6];
    const float* W_dt   = (const float*)d_in[7];
    const float* b_dt   = (const float*)d_in[8];
    const float* W_out  = (const float*)d_in[9];
    float* out = (float*)d_out;

    char* ws = (char*)d_ws;
    // workspace layout (bytes), ~112 MiB, no overlays:
    unsigned short* XZb   = (unsigned short*)(ws + 0);           // 32 MiB  [t1..t7]
    unsigned short* XACTB = (unsigned short*)(ws + 33554432);    // 16 MiB  [t2..t6]
    unsigned short* Xb    = (unsigned short*)(ws + 50331648);    // 8 MiB   [t0..t1]
    unsigned short* W_inb = (unsigned short*)(ws + 58720256);    // 8 MiB   [t0..t1]
    unsigned short* Hbuf  = (unsigned short*)(ws + 67108864);    // 16 MiB  [t4..t6]
    unsigned short* YLOC  = (unsigned short*)(ws + 83886080);    // 16 MiB  [t4..t6]
    float* PROJ  = (float*)(ws + 100663296);                     // 0.56 MiB
    float* DTSUM = (float*)(ws + 101711872);                     // 2 MiB
    float* PROJP = (float*)(ws + 103809024);                     // 2.25 MiB
    float* Abuf  = (float*)(ws + 106954752);                     // 128 KiB
    unsigned short* W_outb = (unsigned short*)(ws + 108003328);  // 4 MiB
    unsigned short* Wxb48  = (unsigned short*)(ws + 112197632);  // 192 KiB

    const int M = BATCH * LSEQ;   // 4096

    // t0) fused converts / prep (one launch)
    prep_all<<<(PREP_A + 255) / 256, 256, 0, stream>>>(
        x, W_in, W_out, W_x, A_log, Xb, W_inb, W_outb, Wxb48, Abuf);

    // t1) xz = x @ W_in.T -> bf16 XZb (128x256, 3-deep counted, 2 blocks/CU)
    gemm1_3d<<<512, 512, 0, stream>>>(Xb, W_inb, XZb);

    // t2) depthwise conv + SiLU -> XACTB (bf16)
    conv_silu<<<BATCH * LSEQ * DI / 8 / 256, 256, 0, stream>>>(XZb, conv_w, conv_b, XACTB);

    // t3) proj
    gemm_proj_mfma<<<dim3(M / 64, 4), 256, 0, stream>>>(XACTB, Wxb48, PROJP);
    proj_combine<<<(M * 33 + 255) / 256, 256, 0, stream>>>(PROJP, PROJ);

    // t4-t6) chunked scan
    scan_phase1<<<dim3(DI / 256, NC, BATCH), 256, 0, stream>>>(
        XACTB, PROJ, Abuf, W_dt, b_dt, Dp, Hbuf, DTSUM, YLOC, XZb);
    scan_phase2<<<BATCH * DS * DI / 256, 256, 0, stream>>>(Hbuf, DTSUM, Abuf);
    scan_phase3<<<dim3(DI / 256, NC, BATCH), 256, 0, stream>>>(
        YLOC, PROJ, Abuf, Hbuf, XZb);

    // t7) out = y @ W_out.T  (A = y in XZb cols 0..2047, lda = 4096)
    gemm3_pipe<<<512, 256, 0, stream>>>(XZb, 4096, W_outb, out);
}